// Round 1
// baseline (39167.218 us; speedup 1.0000x reference)
//
#include <hip/hip_runtime.h>

// ---------------------------------------------------------------------------
// TransitionDown: FPS (M=N/4) -> KNN(K=16) -> Linear(64->128)+ReLU -> max-pool
// Round 1: correctness-first. FPS = single workgroup, register-resident state.
// ---------------------------------------------------------------------------

#define FPS_T   512
#define FPS_PPT 64        // FPS_T * FPS_PPT == N == 32768
#define KNN_K   16
#define MLP_ROWS 32

// --- SoA transpose of pos for coalesced per-coordinate access ---------------
__global__ void prep_kernel(const float* __restrict__ pos, float* __restrict__ posx,
                            float* __restrict__ posy, float* __restrict__ posz, int N)
{
    const int i = blockIdx.x * blockDim.x + threadIdx.x;
    if (i < N) {
        posx[i] = pos[3 * i + 0];
        posy[i] = pos[3 * i + 1];
        posz[i] = pos[3 * i + 2];
    }
}

// --- h = relu(x @ W + b), x[N,64], W[64,128], h[N,128] ----------------------
__global__ __launch_bounds__(256) void mlp_kernel(
    const float* __restrict__ x, const float* __restrict__ W,
    const float* __restrict__ b, float* __restrict__ h, int N)
{
    __shared__ float ws[64 * 128];
    __shared__ float xs[MLP_ROWS * 65];   // +1 pad: breaks 8-way bank conflict
    const int t = threadIdx.x;
    const int r0 = blockIdx.x * MLP_ROWS;

    for (int i = t; i < 64 * 128; i += 256) ws[i] = W[i];
    for (int i = t; i < MLP_ROWS * 64; i += 256) {
        const int r = i >> 6, k = i & 63;
        xs[r * 65 + k] = x[r0 * 64 + i];
    }
    __syncthreads();

    const int tx = t & 31, ty = t >> 5;
    const int c0 = tx * 4, rr = ty * 4;    // 4 rows x 4 cols per thread
    float acc[4][4];
#pragma unroll
    for (int i = 0; i < 4; ++i)
#pragma unroll
        for (int j = 0; j < 4; ++j) acc[i][j] = 0.0f;

    for (int k = 0; k < 64; ++k) {
        const float4 w4 = *(const float4*)(&ws[k * 128 + c0]);
#pragma unroll
        for (int i = 0; i < 4; ++i) {
            const float xv = xs[(rr + i) * 65 + k];
            acc[i][0] += xv * w4.x;
            acc[i][1] += xv * w4.y;
            acc[i][2] += xv * w4.z;
            acc[i][3] += xv * w4.w;
        }
    }
    const float4 b4 = *(const float4*)(&b[c0]);
#pragma unroll
    for (int i = 0; i < 4; ++i) {
        float4 o;
        o.x = fmaxf(acc[i][0] + b4.x, 0.0f);
        o.y = fmaxf(acc[i][1] + b4.y, 0.0f);
        o.z = fmaxf(acc[i][2] + b4.z, 0.0f);
        o.w = fmaxf(acc[i][3] + b4.w, 0.0f);
        *(float4*)(&h[(size_t)(r0 + rr + i) * 128 + c0]) = o;
    }
}

// --- Farthest point sampling: exact sequential semantics --------------------
// idx = [0, pick_0, pick_1, ..., pick_{M-2}]; pick = argmax of updated mind,
// ties -> lowest index (matches jnp.argmax).
__global__ __launch_bounds__(FPS_T) void fps_kernel(
    const float* __restrict__ posx, const float* __restrict__ posy,
    const float* __restrict__ posz, int* __restrict__ out_idx, int M)
{
    const int t = threadIdx.x;
    const int wid = t >> 6;
    const int lane = t & 63;

    // Register-resident state: x, y, mind. z streamed from L2 each step.
    float px[FPS_PPT], py[FPS_PPT], mind[FPS_PPT];
#pragma unroll
    for (int j = 0; j < FPS_PPT; ++j) {
        const int i = j * FPS_T + t;          // strided ownership -> coalesced
        px[j] = posx[i];
        py[j] = posy[i];
        mind[j] = __builtin_inff();
    }

    __shared__ float red_v[FPS_T / 64];
    __shared__ int   red_i[FPS_T / 64];

    if (t == 0) out_idx[0] = 0;
    int last = 0;

    for (int s = 1; s < M; ++s) {
        const float lx = posx[last];
        const float ly = posy[last];
        const float lz = posz[last];

        float best = -1.0f;
        int bi = 0x7fffffff;
#pragma unroll
        for (int j = 0; j < FPS_PPT; ++j) {
            const int i = j * FPS_T + t;
            const float dx = px[j] - lx;
            const float dy = py[j] - ly;
            const float dz = posz[i] - lz;
            const float d = dx * dx + dy * dy + dz * dz;
            const float m = fminf(mind[j], d);
            mind[j] = m;
            if (m > best) { best = m; bi = i; }   // j ascending => lower idx kept on tie
        }
        // wave argmax (value, then lower index)
#pragma unroll
        for (int off = 32; off > 0; off >>= 1) {
            const float ov = __shfl_xor(best, off);
            const int   oi = __shfl_xor(bi, off);
            if (ov > best || (ov == best && oi < bi)) { best = ov; bi = oi; }
        }
        if (lane == 0) { red_v[wid] = best; red_i[wid] = bi; }
        __syncthreads();
        float bv = red_v[0];
        int bidx = red_i[0];
#pragma unroll
        for (int w = 1; w < FPS_T / 64; ++w) {
            const float v = red_v[w];
            const int   i2 = red_i[w];
            if (v > bv || (v == bv && i2 < bidx)) { bv = v; bidx = i2; }
        }
        __syncthreads();                       // WAR guard for red_* next iter
        if (t == 0) out_idx[s] = bidx;
        last = bidx;
    }
}

// --- KNN (exact top-16 by (d, idx)) + gather-max over h + sub outputs -------
__global__ __launch_bounds__(256) void knn_kernel(
    const float* __restrict__ posx, const float* __restrict__ posy,
    const float* __restrict__ posz, const int* __restrict__ idx,
    const float* __restrict__ h, const float* __restrict__ pos,
    const int* __restrict__ batch, float* __restrict__ out,
    float* __restrict__ out_subpos, int* __restrict__ out_subbatch,
    int N, int M, int Cout)
{
    const int q = (int)((blockIdx.x * (unsigned)blockDim.x + threadIdx.x) >> 6);
    const int lane = threadIdx.x & 63;
    if (q >= M) return;

    const int qi = idx[q];
    const float qx = posx[qi], qy = posy[qi], qz = posz[qi];

    // per-lane top-16 (replace-max), wave-shared rejection threshold T
    float d16[KNN_K]; int i16[KNN_K];
#pragma unroll
    for (int k = 0; k < KNN_K; ++k) { d16[k] = __builtin_inff(); i16[k] = 0x7fffffff; }
    float lmax = __builtin_inff();
    int lslot = 0;
    float T = __builtin_inff();

    const int iters = N >> 6;
    for (int c = 0; c < iters; ++c) {
        const int p = c * 64 + lane;
        const float dx = posx[p] - qx;
        const float dy = posy[p] - qy;
        const float dz = posz[p] - qz;
        const float d = dx * dx + dy * dy + dz * dz;
        if (d < T && d < lmax) {
            d16[lslot] = d; i16[lslot] = p;
            lmax = d16[0]; lslot = 0;
#pragma unroll
            for (int k = 1; k < KNN_K; ++k)
                if (d16[k] > lmax) { lmax = d16[k]; lslot = k; }
        }
        if ((c & 31) == 31) {
            float tt = lmax;
#pragma unroll
            for (int off = 32; off > 0; off >>= 1)
                tt = fminf(tt, __shfl_xor(tt, off));
            T = tt;   // global-16th-so-far <= min over lanes of lane-16th: exact reject
        }
    }

    // merge: 16 rounds of wave extract-min with (d, idx) lexicographic order
    int nbr[KNN_K];
#pragma unroll
    for (int r = 0; r < KNN_K; ++r) {
        float lv = d16[0]; int ls = 0;
#pragma unroll
        for (int k = 1; k < KNN_K; ++k)
            if (d16[k] < lv || (d16[k] == lv && i16[k] < i16[ls])) { lv = d16[k]; ls = k; }
        float mv = lv; int mi = i16[ls];
#pragma unroll
        for (int off = 32; off > 0; off >>= 1) {
            const float ov = __shfl_xor(mv, off);
            const int   oi = __shfl_xor(mi, off);
            if (ov < mv || (ov == mv && oi < mi)) { mv = ov; mi = oi; }
        }
        if (i16[ls] == mi) d16[ls] = __builtin_inff();   // unique owner removes it
        nbr[r] = mi;
    }

    // out[q] = max over 16 neighbors of h rows (coalesced per-row loads)
    for (int c = lane; c < Cout; c += 64) {
        float a = -__builtin_inff();
#pragma unroll
        for (int r = 0; r < KNN_K; ++r)
            a = fmaxf(a, h[(size_t)nbr[r] * Cout + c]);
        out[(size_t)q * Cout + c] = a;
    }
    if (lane < 3) out_subpos[q * 3 + lane] = pos[qi * 3 + lane];
    if (lane == 3) out_subbatch[q] = batch[qi];
}

// ---------------------------------------------------------------------------
extern "C" void kernel_launch(void* const* d_in, const int* in_sizes, int n_in,
                              void* d_out, int out_size, void* d_ws, size_t ws_size,
                              hipStream_t stream)
{
    const float* x     = (const float*)d_in[0];
    const float* pos   = (const float*)d_in[1];
    const int*   batch = (const int*)d_in[2];
    const float* W     = (const float*)d_in[3];
    const float* b     = (const float*)d_in[4];

    const int N    = in_sizes[2];       // 32768 (batch has one entry per point)
    const int Cout = in_sizes[4];       // 128
    const int M    = N / 4;             // RATIO = 0.25 -> 8192

    // workspace layout (floats): posx | posy | posz | idx(int) | h[N*Cout]
    float* posx = (float*)d_ws;
    float* posy = posx + N;
    float* posz = posy + N;
    int*   idx  = (int*)(posz + N);
    float* h    = (float*)(idx + M);

    float* out          = (float*)d_out;
    float* out_subpos   = out + (size_t)M * Cout;
    int*   out_subbatch = (int*)(out_subpos + (size_t)M * 3);

    prep_kernel<<<(N + 255) / 256, 256, 0, stream>>>(pos, posx, posy, posz, N);
    mlp_kernel<<<N / MLP_ROWS, 256, 0, stream>>>(x, W, b, h, N);
    fps_kernel<<<1, FPS_T, 0, stream>>>(posx, posy, posz, idx, M);
    knn_kernel<<<(M * 64) / 256, 256, 0, stream>>>(posx, posy, posz, idx, h, pos, batch,
                                                   out, out_subpos, out_subbatch, N, M, Cout);
}

// Round 2
// 33324.680 us; speedup vs baseline: 1.1753x; 1.1753x over previous
//
#include <hip/hip_runtime.h>

// ---------------------------------------------------------------------------
// TransitionDown: FPS (M=N/4) -> KNN(K=16) -> Linear(64->128)+ReLU -> max-pool
// Round 2: fix FPS register spill. __launch_bounds__(512,2) -> 256 VGPR cap
// (per-SIMD pool = 512 regs; 2 waves/EU). State px/py/mind = 192 regs stays
// resident; z streamed from L2. `last` forced scalar for s_load coord fetch.
// ---------------------------------------------------------------------------

#define FPS_T   512
#define FPS_PPT 64        // FPS_T * FPS_PPT == N == 32768
#define KNN_K   16
#define MLP_ROWS 32

// --- SoA transpose of pos for coalesced per-coordinate access ---------------
__global__ void prep_kernel(const float* __restrict__ pos, float* __restrict__ posx,
                            float* __restrict__ posy, float* __restrict__ posz, int N)
{
    const int i = blockIdx.x * blockDim.x + threadIdx.x;
    if (i < N) {
        posx[i] = pos[3 * i + 0];
        posy[i] = pos[3 * i + 1];
        posz[i] = pos[3 * i + 2];
    }
}

// --- h = relu(x @ W + b), x[N,64], W[64,128], h[N,128] ----------------------
__global__ __launch_bounds__(256) void mlp_kernel(
    const float* __restrict__ x, const float* __restrict__ W,
    const float* __restrict__ b, float* __restrict__ h, int N)
{
    __shared__ float ws[64 * 128];
    __shared__ float xs[MLP_ROWS * 65];   // +1 pad: breaks 8-way bank conflict
    const int t = threadIdx.x;
    const int r0 = blockIdx.x * MLP_ROWS;

    for (int i = t; i < 64 * 128; i += 256) ws[i] = W[i];
    for (int i = t; i < MLP_ROWS * 64; i += 256) {
        const int r = i >> 6, k = i & 63;
        xs[r * 65 + k] = x[r0 * 64 + i];
    }
    __syncthreads();

    const int tx = t & 31, ty = t >> 5;
    const int c0 = tx * 4, rr = ty * 4;    // 4 rows x 4 cols per thread
    float acc[4][4];
#pragma unroll
    for (int i = 0; i < 4; ++i)
#pragma unroll
        for (int j = 0; j < 4; ++j) acc[i][j] = 0.0f;

    for (int k = 0; k < 64; ++k) {
        const float4 w4 = *(const float4*)(&ws[k * 128 + c0]);
#pragma unroll
        for (int i = 0; i < 4; ++i) {
            const float xv = xs[(rr + i) * 65 + k];
            acc[i][0] += xv * w4.x;
            acc[i][1] += xv * w4.y;
            acc[i][2] += xv * w4.z;
            acc[i][3] += xv * w4.w;
        }
    }
    const float4 b4 = *(const float4*)(&b[c0]);
#pragma unroll
    for (int i = 0; i < 4; ++i) {
        float4 o;
        o.x = fmaxf(acc[i][0] + b4.x, 0.0f);
        o.y = fmaxf(acc[i][1] + b4.y, 0.0f);
        o.z = fmaxf(acc[i][2] + b4.z, 0.0f);
        o.w = fmaxf(acc[i][3] + b4.w, 0.0f);
        *(float4*)(&h[(size_t)(r0 + rr + i) * 128 + c0]) = o;
    }
}

// --- Farthest point sampling: exact sequential semantics --------------------
// idx = [0, pick_0, ..., pick_{M-2}]; pick = argmax of updated mind,
// ties -> lowest index (matches jnp.argmax).
// __launch_bounds__(512, 2): 2 waves/EU -> 256 VGPR/wave cap. State arrays
// px/py/mind (192 regs) MUST stay in registers — spill was the round-1 4x.
__global__ __launch_bounds__(FPS_T, 2) void fps_kernel(
    const float* __restrict__ posx, const float* __restrict__ posy,
    const float* __restrict__ posz, int* __restrict__ out_idx, int M)
{
    const int t = threadIdx.x;
    const int wid = t >> 6;
    const int lane = t & 63;

    // Register-resident state: x, y, mind. z streamed from L2 each step.
    float px[FPS_PPT], py[FPS_PPT], mind[FPS_PPT];
#pragma unroll
    for (int j = 0; j < FPS_PPT; ++j) {
        const int i = j * FPS_T + t;          // strided ownership -> coalesced
        px[j] = posx[i];
        py[j] = posy[i];
        mind[j] = __builtin_inff();
    }

    __shared__ float red_v[FPS_T / 64];
    __shared__ int   red_i[FPS_T / 64];

    if (t == 0) out_idx[0] = 0;
    int last = 0;

    for (int s = 1; s < M; ++s) {
        // `last` is wave-uniform: force SGPR so coord fetches are s_loads.
        const int lastS = __builtin_amdgcn_readfirstlane(last);
        const float lx = posx[lastS];
        const float ly = posy[lastS];
        const float lz = posz[lastS];

        float best = -1.0f;
        int bi = 0x7fffffff;
#pragma unroll
        for (int j = 0; j < FPS_PPT; ++j) {
            const int i = j * FPS_T + t;
            const float dx = px[j] - lx;
            const float dy = py[j] - ly;
            const float dz = posz[i] - lz;
            const float d = dx * dx + dy * dy + dz * dz;
            const float m = fminf(mind[j], d);
            mind[j] = m;
            if (m > best) { best = m; bi = i; }   // j ascending => lower idx kept on tie
        }
        // wave argmax (value, then lower index)
#pragma unroll
        for (int off = 32; off > 0; off >>= 1) {
            const float ov = __shfl_xor(best, off);
            const int   oi = __shfl_xor(bi, off);
            if (ov > best || (ov == best && oi < bi)) { best = ov; bi = oi; }
        }
        if (lane == 0) { red_v[wid] = best; red_i[wid] = bi; }
        __syncthreads();
        float bv = red_v[0];
        int bidx = red_i[0];
#pragma unroll
        for (int w = 1; w < FPS_T / 64; ++w) {
            const float v = red_v[w];
            const int   i2 = red_i[w];
            if (v > bv || (v == bv && i2 < bidx)) { bv = v; bidx = i2; }
        }
        __syncthreads();                       // WAR guard for red_* next iter
        if (t == 0) out_idx[s] = bidx;
        last = bidx;
    }
}

// --- KNN (exact top-16 by (d, idx)) + gather-max over h + sub outputs -------
__global__ __launch_bounds__(256) void knn_kernel(
    const float* __restrict__ posx, const float* __restrict__ posy,
    const float* __restrict__ posz, const int* __restrict__ idx,
    const float* __restrict__ h, const float* __restrict__ pos,
    const int* __restrict__ batch, float* __restrict__ out,
    float* __restrict__ out_subpos, int* __restrict__ out_subbatch,
    int N, int M, int Cout)
{
    const int q = (int)((blockIdx.x * (unsigned)blockDim.x + threadIdx.x) >> 6);
    const int lane = threadIdx.x & 63;
    if (q >= M) return;

    const int qi = idx[q];
    const float qx = posx[qi], qy = posy[qi], qz = posz[qi];

    // per-lane top-16 (replace-max), wave-shared rejection threshold T
    float d16[KNN_K]; int i16[KNN_K];
#pragma unroll
    for (int k = 0; k < KNN_K; ++k) { d16[k] = __builtin_inff(); i16[k] = 0x7fffffff; }
    float lmax = __builtin_inff();
    int lslot = 0;
    float T = __builtin_inff();

    const int iters = N >> 6;
    for (int c = 0; c < iters; ++c) {
        const int p = c * 64 + lane;
        const float dx = posx[p] - qx;
        const float dy = posy[p] - qy;
        const float dz = posz[p] - qz;
        const float d = dx * dx + dy * dy + dz * dz;
        if (d < T && d < lmax) {
            d16[lslot] = d; i16[lslot] = p;
            lmax = d16[0]; lslot = 0;
#pragma unroll
            for (int k = 1; k < KNN_K; ++k)
                if (d16[k] > lmax) { lmax = d16[k]; lslot = k; }
        }
        if ((c & 31) == 31) {
            float tt = lmax;
#pragma unroll
            for (int off = 32; off > 0; off >>= 1)
                tt = fminf(tt, __shfl_xor(tt, off));
            T = tt;   // global-16th-so-far <= min over lanes of lane-16th: exact reject
        }
    }

    // merge: 16 rounds of wave extract-min with (d, idx) lexicographic order
    int nbr[KNN_K];
#pragma unroll
    for (int r = 0; r < KNN_K; ++r) {
        float lv = d16[0]; int ls = 0;
#pragma unroll
        for (int k = 1; k < KNN_K; ++k)
            if (d16[k] < lv || (d16[k] == lv && i16[k] < i16[ls])) { lv = d16[k]; ls = k; }
        float mv = lv; int mi = i16[ls];
#pragma unroll
        for (int off = 32; off > 0; off >>= 1) {
            const float ov = __shfl_xor(mv, off);
            const int   oi = __shfl_xor(mi, off);
            if (ov < mv || (ov == mv && oi < mi)) { mv = ov; mi = oi; }
        }
        if (i16[ls] == mi) d16[ls] = __builtin_inff();   // unique owner removes it
        nbr[r] = mi;
    }

    // out[q] = max over 16 neighbors of h rows (coalesced per-row loads)
    for (int c = lane; c < Cout; c += 64) {
        float a = -__builtin_inff();
#pragma unroll
        for (int r = 0; r < KNN_K; ++r)
            a = fmaxf(a, h[(size_t)nbr[r] * Cout + c]);
        out[(size_t)q * Cout + c] = a;
    }
    if (lane < 3) out_subpos[q * 3 + lane] = pos[qi * 3 + lane];
    if (lane == 3) out_subbatch[q] = batch[qi];
}

// ---------------------------------------------------------------------------
extern "C" void kernel_launch(void* const* d_in, const int* in_sizes, int n_in,
                              void* d_out, int out_size, void* d_ws, size_t ws_size,
                              hipStream_t stream)
{
    const float* x     = (const float*)d_in[0];
    const float* pos   = (const float*)d_in[1];
    const int*   batch = (const int*)d_in[2];
    const float* W     = (const float*)d_in[3];
    const float* b     = (const float*)d_in[4];

    const int N    = in_sizes[2];       // 32768 (batch has one entry per point)
    const int Cout = in_sizes[4];       // 128
    const int M    = N / 4;             // RATIO = 0.25 -> 8192

    // workspace layout (floats): posx | posy | posz | idx(int) | h[N*Cout]
    float* posx = (float*)d_ws;
    float* posy = posx + N;
    float* posz = posy + N;
    int*   idx  = (int*)(posz + N);
    float* h    = (float*)(idx + M);

    float* out          = (float*)d_out;
    float* out_subpos   = out + (size_t)M * Cout;
    int*   out_subbatch = (int*)(out_subpos + (size_t)M * 3);

    prep_kernel<<<(N + 255) / 256, 256, 0, stream>>>(pos, posx, posy, posz, N);
    mlp_kernel<<<N / MLP_ROWS, 256, 0, stream>>>(x, W, b, h, N);
    fps_kernel<<<1, FPS_T, 0, stream>>>(posx, posy, posz, idx, M);
    knn_kernel<<<(M * 64) / 256, 256, 0, stream>>>(posx, posy, posz, idx, h, pos, batch,
                                                   out, out_subpos, out_subbatch, N, M, Cout);
}

// Round 3
// 33119.073 us; speedup vs baseline: 1.1826x; 1.0062x over previous
//
#include <hip/hip_runtime.h>

// ---------------------------------------------------------------------------
// TransitionDown: FPS (M=N/4) -> KNN(K=16) -> Linear(64->128)+ReLU -> max-pool
// Round 3: FPS state as ext_vector_type SSA values (not allocas). Round-2
// post-mortem: float arrays px[64]/py[64]/mind[64] were lowered to scratch by
// SROA (loop-variant indices before unroll) -> 512KB/step L2 round-trip
// ~= 4us/step. Vectors are SSA; they cannot silently live in scratch.
// ---------------------------------------------------------------------------

#define FPS_T   512
#define KNN_K   16
#define MLP_ROWS 32

typedef float vf16 __attribute__((ext_vector_type(16)));

// --- SoA transpose of pos for coalesced per-coordinate access ---------------
__global__ void prep_kernel(const float* __restrict__ pos, float* __restrict__ posx,
                            float* __restrict__ posy, float* __restrict__ posz, int N)
{
    const int i = blockIdx.x * blockDim.x + threadIdx.x;
    if (i < N) {
        posx[i] = pos[3 * i + 0];
        posy[i] = pos[3 * i + 1];
        posz[i] = pos[3 * i + 2];
    }
}

// --- h = relu(x @ W + b), x[N,64], W[64,128], h[N,128] ----------------------
__global__ __launch_bounds__(256) void mlp_kernel(
    const float* __restrict__ x, const float* __restrict__ W,
    const float* __restrict__ b, float* __restrict__ h, int N)
{
    __shared__ float ws[64 * 128];
    __shared__ float xs[MLP_ROWS * 65];   // +1 pad: breaks 8-way bank conflict
    const int t = threadIdx.x;
    const int r0 = blockIdx.x * MLP_ROWS;

    for (int i = t; i < 64 * 128; i += 256) ws[i] = W[i];
    for (int i = t; i < MLP_ROWS * 64; i += 256) {
        const int r = i >> 6, k = i & 63;
        xs[r * 65 + k] = x[r0 * 64 + i];
    }
    __syncthreads();

    const int tx = t & 31, ty = t >> 5;
    const int c0 = tx * 4, rr = ty * 4;    // 4 rows x 4 cols per thread
    float acc[4][4];
#pragma unroll
    for (int i = 0; i < 4; ++i)
#pragma unroll
        for (int j = 0; j < 4; ++j) acc[i][j] = 0.0f;

    for (int k = 0; k < 64; ++k) {
        const float4 w4 = *(const float4*)(&ws[k * 128 + c0]);
#pragma unroll
        for (int i = 0; i < 4; ++i) {
            const float xv = xs[(rr + i) * 65 + k];
            acc[i][0] += xv * w4.x;
            acc[i][1] += xv * w4.y;
            acc[i][2] += xv * w4.z;
            acc[i][3] += xv * w4.w;
        }
    }
    const float4 b4 = *(const float4*)(&b[c0]);
#pragma unroll
    for (int i = 0; i < 4; ++i) {
        float4 o;
        o.x = fmaxf(acc[i][0] + b4.x, 0.0f);
        o.y = fmaxf(acc[i][1] + b4.y, 0.0f);
        o.z = fmaxf(acc[i][2] + b4.z, 0.0f);
        o.w = fmaxf(acc[i][3] + b4.w, 0.0f);
        *(float4*)(&h[(size_t)(r0 + rr + i) * 128 + c0]) = o;
    }
}

// --- Farthest point sampling: exact sequential semantics --------------------
// idx = [0, pick_0, ..., pick_{M-2}]; pick = argmax of updated mind,
// ties -> lowest index (matches jnp.argmax).
// State: 12 x float16 vectors = 192 VGPRs of SSA values. launch_bounds(512,2)
// gives the RA a 256-reg budget (2 waves/EU min).
#define FPS_INIT(PX, PY, MD, BASE)                          \
    _Pragma("unroll")                                       \
    for (int e = 0; e < 16; ++e) {                          \
        const int i = (BASE + e) * FPS_T + t;               \
        PX[e] = posx[i];                                    \
        PY[e] = posy[i];                                    \
        MD[e] = __builtin_inff();                           \
    }

#define FPS_STEP(PX, PY, MD, BASE)                          \
    _Pragma("unroll")                                       \
    for (int e = 0; e < 16; ++e) {                          \
        const int i = (BASE + e) * FPS_T + t;               \
        const float dx = PX[e] - lx;                        \
        const float dy = PY[e] - ly;                        \
        const float dz = posz[i] - lz;                      \
        const float d = dx * dx + dy * dy + dz * dz;        \
        const float m = fminf(MD[e], d);                    \
        MD[e] = m;                                          \
        if (m > best) { best = m; bi = i; }                 \
    }

__global__ __launch_bounds__(FPS_T, 2) void fps_kernel(
    const float* __restrict__ posx, const float* __restrict__ posy,
    const float* __restrict__ posz, int* __restrict__ out_idx, int M)
{
    const int t = threadIdx.x;
    const int wid = t >> 6;
    const int lane = t & 63;

    vf16 px0, px1, px2, px3, py0, py1, py2, py3, md0, md1, md2, md3;
    FPS_INIT(px0, py0, md0, 0)
    FPS_INIT(px1, py1, md1, 16)
    FPS_INIT(px2, py2, md2, 32)
    FPS_INIT(px3, py3, md3, 48)

    __shared__ float red_v[FPS_T / 64];
    __shared__ int   red_i[FPS_T / 64];

    if (t == 0) out_idx[0] = 0;
    int last = 0;

    for (int s = 1; s < M; ++s) {
        // `last` is wave-uniform: force SGPR so coord fetches are s_loads.
        const int lastS = __builtin_amdgcn_readfirstlane(last);
        const float lx = posx[lastS];
        const float ly = posy[lastS];
        const float lz = posz[lastS];

        float best = -1.0f;
        int bi = 0x7fffffff;
        // ascending global index within a thread => strict '>' keeps lowest on tie
        FPS_STEP(px0, py0, md0, 0)
        FPS_STEP(px1, py1, md1, 16)
        FPS_STEP(px2, py2, md2, 32)
        FPS_STEP(px3, py3, md3, 48)

        // wave argmax (value, then lower index)
#pragma unroll
        for (int off = 32; off > 0; off >>= 1) {
            const float ov = __shfl_xor(best, off);
            const int   oi = __shfl_xor(bi, off);
            if (ov > best || (ov == best && oi < bi)) { best = ov; bi = oi; }
        }
        if (lane == 0) { red_v[wid] = best; red_i[wid] = bi; }
        __syncthreads();
        float bv = red_v[0];
        int bidx = red_i[0];
#pragma unroll
        for (int w = 1; w < FPS_T / 64; ++w) {
            const float v = red_v[w];
            const int   i2 = red_i[w];
            if (v > bv || (v == bv && i2 < bidx)) { bv = v; bidx = i2; }
        }
        __syncthreads();                       // WAR guard for red_* next iter
        if (t == 0) out_idx[s] = bidx;
        last = bidx;
    }
}

// --- KNN (exact top-16 by (d, idx)) + gather-max over h + sub outputs -------
__global__ __launch_bounds__(256) void knn_kernel(
    const float* __restrict__ posx, const float* __restrict__ posy,
    const float* __restrict__ posz, const int* __restrict__ idx,
    const float* __restrict__ h, const float* __restrict__ pos,
    const int* __restrict__ batch, float* __restrict__ out,
    float* __restrict__ out_subpos, int* __restrict__ out_subbatch,
    int N, int M, int Cout)
{
    const int q = (int)((blockIdx.x * (unsigned)blockDim.x + threadIdx.x) >> 6);
    const int lane = threadIdx.x & 63;
    if (q >= M) return;

    const int qi = idx[q];
    const float qx = posx[qi], qy = posy[qi], qz = posz[qi];

    // per-lane top-16 (replace-max), wave-shared rejection threshold T
    float d16[KNN_K]; int i16[KNN_K];
#pragma unroll
    for (int k = 0; k < KNN_K; ++k) { d16[k] = __builtin_inff(); i16[k] = 0x7fffffff; }
    float lmax = __builtin_inff();
    int lslot = 0;
    float T = __builtin_inff();

    const int iters = N >> 6;
    for (int c = 0; c < iters; ++c) {
        const int p = c * 64 + lane;
        const float dx = posx[p] - qx;
        const float dy = posy[p] - qy;
        const float dz = posz[p] - qz;
        const float d = dx * dx + dy * dy + dz * dz;
        if (d < T && d < lmax) {
            d16[lslot] = d; i16[lslot] = p;
            lmax = d16[0]; lslot = 0;
#pragma unroll
            for (int k = 1; k < KNN_K; ++k)
                if (d16[k] > lmax) { lmax = d16[k]; lslot = k; }
        }
        if ((c & 31) == 31) {
            float tt = lmax;
#pragma unroll
            for (int off = 32; off > 0; off >>= 1)
                tt = fminf(tt, __shfl_xor(tt, off));
            T = tt;   // global-16th-so-far <= min over lanes of lane-16th: exact reject
        }
    }

    // merge: 16 rounds of wave extract-min with (d, idx) lexicographic order
    int nbr[KNN_K];
#pragma unroll
    for (int r = 0; r < KNN_K; ++r) {
        float lv = d16[0]; int ls = 0;
#pragma unroll
        for (int k = 1; k < KNN_K; ++k)
            if (d16[k] < lv || (d16[k] == lv && i16[k] < i16[ls])) { lv = d16[k]; ls = k; }
        float mv = lv; int mi = i16[ls];
#pragma unroll
        for (int off = 32; off > 0; off >>= 1) {
            const float ov = __shfl_xor(mv, off);
            const int   oi = __shfl_xor(mi, off);
            if (ov < mv || (ov == mv && oi < mi)) { mv = ov; mi = oi; }
        }
        if (i16[ls] == mi) d16[ls] = __builtin_inff();   // unique owner removes it
        nbr[r] = mi;
    }

    // out[q] = max over 16 neighbors of h rows (coalesced per-row loads)
    for (int c = lane; c < Cout; c += 64) {
        float a = -__builtin_inff();
#pragma unroll
        for (int r = 0; r < KNN_K; ++r)
            a = fmaxf(a, h[(size_t)nbr[r] * Cout + c]);
        out[(size_t)q * Cout + c] = a;
    }
    if (lane < 3) out_subpos[q * 3 + lane] = pos[qi * 3 + lane];
    if (lane == 3) out_subbatch[q] = batch[qi];
}

// ---------------------------------------------------------------------------
extern "C" void kernel_launch(void* const* d_in, const int* in_sizes, int n_in,
                              void* d_out, int out_size, void* d_ws, size_t ws_size,
                              hipStream_t stream)
{
    const float* x     = (const float*)d_in[0];
    const float* pos   = (const float*)d_in[1];
    const int*   batch = (const int*)d_in[2];
    const float* W     = (const float*)d_in[3];
    const float* b     = (const float*)d_in[4];

    const int N    = in_sizes[2];       // 32768 (batch has one entry per point)
    const int Cout = in_sizes[4];       // 128
    const int M    = N / 4;             // RATIO = 0.25 -> 8192

    // workspace layout (floats): posx | posy | posz | idx(int) | h[N*Cout]
    float* posx = (float*)d_ws;
    float* posy = posx + N;
    float* posz = posy + N;
    int*   idx  = (int*)(posz + N);
    float* h    = (float*)(idx + M);

    float* out          = (float*)d_out;
    float* out_subpos   = out + (size_t)M * Cout;
    int*   out_subbatch = (int*)(out_subpos + (size_t)M * 3);

    prep_kernel<<<(N + 255) / 256, 256, 0, stream>>>(pos, posx, posy, posz, N);
    mlp_kernel<<<N / MLP_ROWS, 256, 0, stream>>>(x, W, b, h, N);
    fps_kernel<<<1, FPS_T, 0, stream>>>(posx, posy, posz, idx, M);
    knn_kernel<<<(M * 64) / 256, 256, 0, stream>>>(posx, posy, posz, idx, h, pos, batch,
                                                   out, out_subpos, out_subbatch, N, M, Cout);
}

// Round 4
// 31481.158 us; speedup vs baseline: 1.2441x; 1.0520x over previous
//
#include <hip/hip_runtime.h>

// ---------------------------------------------------------------------------
// TransitionDown: FPS (M=N/4) -> KNN(K=16) -> Linear(64->128)+ReLU -> max-pool
// Round 4: pin FPS register budget with amdgpu_waves_per_eu(2,2) -> 256 VGPR
// cap (512-reg SIMD pool / 2 waves). Rounds 1-3 allocated exactly 128 and
// spilled the 192-reg state to scratch (~512KB/step via L2 = 3.9us/step,
// matching observed). launch_bounds(512,2) did NOT lower the occupancy
// target; the clang attribute is the direct control.
// Also: float4 z-stream (ownership i = j*2048+4t+c, ascending per thread),
// packed-pos s_load for the picked point, double-buffered reduction (1
// barrier/step).
// ---------------------------------------------------------------------------

#define FPS_T   512
#define KNN_K   16
#define MLP_ROWS 32

typedef float vf16 __attribute__((ext_vector_type(16)));

// --- SoA transpose of pos for coalesced per-coordinate access ---------------
__global__ void prep_kernel(const float* __restrict__ pos, float* __restrict__ posx,
                            float* __restrict__ posy, float* __restrict__ posz, int N)
{
    const int i = blockIdx.x * blockDim.x + threadIdx.x;
    if (i < N) {
        posx[i] = pos[3 * i + 0];
        posy[i] = pos[3 * i + 1];
        posz[i] = pos[3 * i + 2];
    }
}

// --- h = relu(x @ W + b), x[N,64], W[64,128], h[N,128] ----------------------
__global__ __launch_bounds__(256) void mlp_kernel(
    const float* __restrict__ x, const float* __restrict__ W,
    const float* __restrict__ b, float* __restrict__ h, int N)
{
    __shared__ float ws[64 * 128];
    __shared__ float xs[MLP_ROWS * 65];   // +1 pad: breaks 8-way bank conflict
    const int t = threadIdx.x;
    const int r0 = blockIdx.x * MLP_ROWS;

    for (int i = t; i < 64 * 128; i += 256) ws[i] = W[i];
    for (int i = t; i < MLP_ROWS * 64; i += 256) {
        const int r = i >> 6, k = i & 63;
        xs[r * 65 + k] = x[r0 * 64 + i];
    }
    __syncthreads();

    const int tx = t & 31, ty = t >> 5;
    const int c0 = tx * 4, rr = ty * 4;    // 4 rows x 4 cols per thread
    float acc[4][4];
#pragma unroll
    for (int i = 0; i < 4; ++i)
#pragma unroll
        for (int j = 0; j < 4; ++j) acc[i][j] = 0.0f;

    for (int k = 0; k < 64; ++k) {
        const float4 w4 = *(const float4*)(&ws[k * 128 + c0]);
#pragma unroll
        for (int i = 0; i < 4; ++i) {
            const float xv = xs[(rr + i) * 65 + k];
            acc[i][0] += xv * w4.x;
            acc[i][1] += xv * w4.y;
            acc[i][2] += xv * w4.z;
            acc[i][3] += xv * w4.w;
        }
    }
    const float4 b4 = *(const float4*)(&b[c0]);
#pragma unroll
    for (int i = 0; i < 4; ++i) {
        float4 o;
        o.x = fmaxf(acc[i][0] + b4.x, 0.0f);
        o.y = fmaxf(acc[i][1] + b4.y, 0.0f);
        o.z = fmaxf(acc[i][2] + b4.z, 0.0f);
        o.w = fmaxf(acc[i][3] + b4.w, 0.0f);
        *(float4*)(&h[(size_t)(r0 + rr + i) * 128 + c0]) = o;
    }
}

// --- Farthest point sampling: exact sequential semantics --------------------
// idx = [0, pick_0, ..., pick_{M-2}]; pick = argmax of updated mind,
// ties -> lowest index (matches jnp.argmax).
// Ownership: thread t, slot k in [0,64): i = (k>>2)*2048 + 4t + (k&3).
// Ascending i per thread => strict '>' keeps lowest index on tie.
#define FPS_INIT(PX, PY, MD, VBASE)                                       \
    _Pragma("unroll")                                                     \
    for (int jj = 0; jj < 4; ++jj) {                                      \
        const int j = (VBASE >> 2) + jj;                                  \
        const float4 x4 = *(const float4*)&posx[j * 2048 + (t << 2)];     \
        const float4 y4 = *(const float4*)&posy[j * 2048 + (t << 2)];     \
        PX[jj * 4 + 0] = x4.x; PX[jj * 4 + 1] = x4.y;                     \
        PX[jj * 4 + 2] = x4.z; PX[jj * 4 + 3] = x4.w;                     \
        PY[jj * 4 + 0] = y4.x; PY[jj * 4 + 1] = y4.y;                     \
        PY[jj * 4 + 2] = y4.z; PY[jj * 4 + 3] = y4.w;                     \
        _Pragma("unroll")                                                 \
        for (int c = 0; c < 4; ++c) MD[jj * 4 + c] = __builtin_inff();    \
    }

#define FPS_STEP(PX, PY, MD, VBASE)                                      \
    _Pragma("unroll")                                                    \
    for (int jj = 0; jj < 4; ++jj) {                                     \
        const int j = (VBASE >> 2) + jj;                                 \
        const float4 z4 = *(const float4*)&posz[j * 2048 + (t << 2)];    \
        _Pragma("unroll")                                                \
        for (int c = 0; c < 4; ++c) {                                    \
            const int e = jj * 4 + c;                                    \
            const int i = j * 2048 + (t << 2) + c;                       \
            const float zc = (c == 0) ? z4.x : (c == 1) ? z4.y           \
                           : (c == 2) ? z4.z : z4.w;                     \
            const float dx = PX[e] - lx;                                 \
            const float dy = PY[e] - ly;                                 \
            const float dz = zc - lz;                                    \
            const float d = dx * dx + dy * dy + dz * dz;                 \
            const float m = fminf(MD[e], d);                             \
            MD[e] = m;                                                   \
            if (m > best) { best = m; bi = i; }                          \
        }                                                                \
    }

__global__ __launch_bounds__(FPS_T)
__attribute__((amdgpu_waves_per_eu(2, 2)))
void fps_kernel(
    const float* __restrict__ posx, const float* __restrict__ posy,
    const float* __restrict__ posz, const float* __restrict__ pos,
    int* __restrict__ out_idx, int M)
{
    const int t = threadIdx.x;
    const int wid = t >> 6;
    const int lane = t & 63;

    vf16 px0, px1, px2, px3, py0, py1, py2, py3, md0, md1, md2, md3;
    FPS_INIT(px0, py0, md0, 0)
    FPS_INIT(px1, py1, md1, 16)
    FPS_INIT(px2, py2, md2, 32)
    FPS_INIT(px3, py3, md3, 48)

    // double-buffered reduction scratch: one barrier per step
    __shared__ float red_v[2][FPS_T / 64];
    __shared__ int   red_i[2][FPS_T / 64];

    if (t == 0) out_idx[0] = 0;
    int last = 0;

    for (int s = 1; s < M; ++s) {
        // wave-uniform pick: fetch its packed coords (one cache line, s_load)
        const int lastS = __builtin_amdgcn_readfirstlane(last);
        const float lx = pos[3 * lastS + 0];
        const float ly = pos[3 * lastS + 1];
        const float lz = pos[3 * lastS + 2];

        float best = -1.0f;
        int bi = 0x7fffffff;
        FPS_STEP(px0, py0, md0, 0)
        FPS_STEP(px1, py1, md1, 16)
        FPS_STEP(px2, py2, md2, 32)
        FPS_STEP(px3, py3, md3, 48)

        // wave argmax (value, then lower index)
#pragma unroll
        for (int off = 32; off > 0; off >>= 1) {
            const float ov = __shfl_xor(best, off);
            const int   oi = __shfl_xor(bi, off);
            if (ov > best || (ov == best && oi < bi)) { best = ov; bi = oi; }
        }
        const int buf = s & 1;
        if (lane == 0) { red_v[buf][wid] = best; red_i[buf][wid] = bi; }
        __syncthreads();
        float bv = red_v[buf][0];
        int bidx = red_i[buf][0];
#pragma unroll
        for (int w = 1; w < FPS_T / 64; ++w) {
            const float v = red_v[buf][w];
            const int   i2 = red_i[buf][w];
            if (v > bv || (v == bv && i2 < bidx)) { bv = v; bidx = i2; }
        }
        if (t == 0) out_idx[s] = bidx;
        last = bidx;
        // no second barrier: next step writes the other red_* buffer
    }
}

// --- KNN (exact top-16 by (d, idx)) + gather-max over h + sub outputs -------
__global__ __launch_bounds__(256) void knn_kernel(
    const float* __restrict__ posx, const float* __restrict__ posy,
    const float* __restrict__ posz, const int* __restrict__ idx,
    const float* __restrict__ h, const float* __restrict__ pos,
    const int* __restrict__ batch, float* __restrict__ out,
    float* __restrict__ out_subpos, int* __restrict__ out_subbatch,
    int N, int M, int Cout)
{
    const int q = (int)((blockIdx.x * (unsigned)blockDim.x + threadIdx.x) >> 6);
    const int lane = threadIdx.x & 63;
    if (q >= M) return;

    const int qi = idx[q];
    const float qx = posx[qi], qy = posy[qi], qz = posz[qi];

    // per-lane top-16 (replace-max), wave-shared rejection threshold T
    float d16[KNN_K]; int i16[KNN_K];
#pragma unroll
    for (int k = 0; k < KNN_K; ++k) { d16[k] = __builtin_inff(); i16[k] = 0x7fffffff; }
    float lmax = __builtin_inff();
    int lslot = 0;
    float T = __builtin_inff();

    const int iters = N >> 6;
    for (int c = 0; c < iters; ++c) {
        const int p = c * 64 + lane;
        const float dx = posx[p] - qx;
        const float dy = posy[p] - qy;
        const float dz = posz[p] - qz;
        const float d = dx * dx + dy * dy + dz * dz;
        if (d < T && d < lmax) {
            d16[lslot] = d; i16[lslot] = p;
            lmax = d16[0]; lslot = 0;
#pragma unroll
            for (int k = 1; k < KNN_K; ++k)
                if (d16[k] > lmax) { lmax = d16[k]; lslot = k; }
        }
        if ((c & 31) == 31) {
            float tt = lmax;
#pragma unroll
            for (int off = 32; off > 0; off >>= 1)
                tt = fminf(tt, __shfl_xor(tt, off));
            T = tt;   // global-16th-so-far <= min over lanes of lane-16th: exact reject
        }
    }

    // merge: 16 rounds of wave extract-min with (d, idx) lexicographic order
    int nbr[KNN_K];
#pragma unroll
    for (int r = 0; r < KNN_K; ++r) {
        float lv = d16[0]; int ls = 0;
#pragma unroll
        for (int k = 1; k < KNN_K; ++k)
            if (d16[k] < lv || (d16[k] == lv && i16[k] < i16[ls])) { lv = d16[k]; ls = k; }
        float mv = lv; int mi = i16[ls];
#pragma unroll
        for (int off = 32; off > 0; off >>= 1) {
            const float ov = __shfl_xor(mv, off);
            const int   oi = __shfl_xor(mi, off);
            if (ov < mv || (ov == mv && oi < mi)) { mv = ov; mi = oi; }
        }
        if (i16[ls] == mi) d16[ls] = __builtin_inff();   // unique owner removes it
        nbr[r] = mi;
    }

    // out[q] = max over 16 neighbors of h rows (coalesced per-row loads)
    for (int c = lane; c < Cout; c += 64) {
        float a = -__builtin_inff();
#pragma unroll
        for (int r = 0; r < KNN_K; ++r)
            a = fmaxf(a, h[(size_t)nbr[r] * Cout + c]);
        out[(size_t)q * Cout + c] = a;
    }
    if (lane < 3) out_subpos[q * 3 + lane] = pos[qi * 3 + lane];
    if (lane == 3) out_subbatch[q] = batch[qi];
}

// ---------------------------------------------------------------------------
extern "C" void kernel_launch(void* const* d_in, const int* in_sizes, int n_in,
                              void* d_out, int out_size, void* d_ws, size_t ws_size,
                              hipStream_t stream)
{
    const float* x     = (const float*)d_in[0];
    const float* pos   = (const float*)d_in[1];
    const int*   batch = (const int*)d_in[2];
    const float* W     = (const float*)d_in[3];
    const float* b     = (const float*)d_in[4];

    const int N    = in_sizes[2];       // 32768 (batch has one entry per point)
    const int Cout = in_sizes[4];       // 128
    const int M    = N / 4;             // RATIO = 0.25 -> 8192

    // workspace layout (floats): posx | posy | posz | idx(int) | h[N*Cout]
    float* posx = (float*)d_ws;
    float* posy = posx + N;
    float* posz = posy + N;
    int*   idx  = (int*)(posz + N);
    float* h    = (float*)(idx + M);

    float* out          = (float*)d_out;
    float* out_subpos   = out + (size_t)M * Cout;
    int*   out_subbatch = (int*)(out_subpos + (size_t)M * 3);

    prep_kernel<<<(N + 255) / 256, 256, 0, stream>>>(pos, posx, posy, posz, N);
    mlp_kernel<<<N / MLP_ROWS, 256, 0, stream>>>(x, W, b, h, N);
    fps_kernel<<<1, FPS_T, 0, stream>>>(posx, posy, posz, pos, idx, M);
    knn_kernel<<<(M * 64) / 256, 256, 0, stream>>>(posx, posy, posz, idx, h, pos, batch,
                                                   out, out_subpos, out_subbatch, N, M, Cout);
}